// Round 1
// baseline (472.597 us; speedup 1.0000x reference)
//
#include <hip/hip_runtime.h>
#include <math.h>

#define BB 8
#define LL 2048
#define DM 512
#define DI 1024
#define NS 16
#define DC 4
#define RK 32
#define NI 11
#define PRED 96
#define NC 7

// ws layout (float offsets)
static constexpr size_t OFF_WF  = 0;          // 11*2048 fused W_in@W_inproj
static constexpr size_t OFF_BF  = 22528;      // 2048    fused b_in@W_inproj
static constexpr size_t OFF_A2  = 24576;      // 1024*16 A * log2(e)
static constexpr size_t OFF_WOF = 40960;      // 1024*7  W_out@W_fc
static constexpr size_t OFF_CWT = 48128;      // 4*1024  conv_w transposed
static constexpr size_t OFF_WXT = 52224;      // 64*1024 W_xproj transposed
static constexpr size_t OFF_U   = 117760;     // 8*2048*1024 u (post conv+silu)
static constexpr size_t OFF_DT  = 16894976;   // 8*2048*1024 dt (post softplus)
static constexpr size_t OFF_BC  = 33672192;   // 8*2048*16
static constexpr size_t OFF_CC  = 33934336;   // 8*2048*16
static constexpr size_t OFF_YS  = 34196480;   // 8*96*1024 scan y output
// total = 34982912 floats = 133.5 MB

__device__ __forceinline__ float fexp2(float x) {
#if __has_builtin(__builtin_amdgcn_exp2f)
  return __builtin_amdgcn_exp2f(x);
#else
  return exp2f(x);
#endif
}
__device__ __forceinline__ float fsilu(float x) {
  return x / (1.f + __expf(-x));
}

// ---------------- precompute fused weights ----------------
__global__ __launch_bounds__(256) void k_pre(
    const float* __restrict__ W_in, const float* __restrict__ b_in,
    const float* __restrict__ W_inproj, const float* __restrict__ conv_w,
    const float* __restrict__ W_xproj, const float* __restrict__ A_log,
    const float* __restrict__ W_out, const float* __restrict__ W_fc,
    float* __restrict__ ws) {
  int bid = blockIdx.x, tid = threadIdx.x;
  if (bid < 96) {                       // Wf (11x2048) rows 0..10, row 11 = bf
    int idx = bid * 256 + tid;
    int r = idx >> 11, c = idx & 2047;
    float acc = 0.f;
    if (r < NI) {
      for (int k = 0; k < DM; ++k) acc = fmaf(W_in[r * DM + k], W_inproj[k * 2 * DI + c], acc);
      ws[OFF_WF + (size_t)r * 2 * DI + c] = acc;
    } else {
      for (int k = 0; k < DM; ++k) acc = fmaf(b_in[k], W_inproj[k * 2 * DI + c], acc);
      ws[OFF_BF + c] = acc;
    }
  } else if (bid < 160) {               // A2 = -exp(A_log)*log2e
    int idx = (bid - 96) * 256 + tid;   // 16384
    ws[OFF_A2 + idx] = -expf(A_log[idx]) * 1.4426950408889634f;
  } else if (bid < 188) {               // Wof = W_out @ W_fc (1024x7)
    int idx = (bid - 160) * 256 + tid;  // 7168
    int d = idx / NC, c = idx - d * NC;
    float acc = 0.f;
    for (int k = 0; k < DM; ++k) acc = fmaf(W_out[d * DM + k], W_fc[k * NC + c], acc);
    ws[OFF_WOF + idx] = acc;
  } else if (bid < 204) {               // conv_w transpose -> [4][1024]
    int idx = (bid - 188) * 256 + tid;  // 4096
    int k = idx >> 10, d = idx & 1023;
    ws[OFF_CWT + idx] = conv_w[d * DC + k];
  } else {                              // W_xproj transpose -> [64][1024]
    int idx = (bid - 204) * 256 + tid;  // 65536
    int c = idx >> 10, k = idx & 1023;
    ws[OFF_WXT + idx] = W_xproj[k * 64 + c];
  }
}

// ---------------- u = silu(causal_conv(in_proj_u(cat)) + conv_b) ----------------
__global__ __launch_bounds__(256) void k_u(
    const float* __restrict__ xe, const float* __restrict__ xm,
    const float* __restrict__ conv_b, float* __restrict__ ws) {
  __shared__ float scat[DC][NI];
  int bid = blockIdx.x, tid = threadIdx.x;
  int tlin = bid >> 2;                  // b*L + t
  int b = tlin >> 11, t = tlin & (LL - 1);
  int d = ((bid & 3) << 8) + tid;
  if (tid < DC * NI) {
    int k = tid / NI, i = tid - k * NI;
    int tp = t - (DC - 1) + k;
    float v = 0.f;
    if (tp >= 0) v = (i < 7) ? xe[(size_t)(b * LL + tp) * 7 + i]
                             : xm[(size_t)(b * LL + tp) * 4 + (i - 7)];
    scat[k][i] = v;
  }
  __syncthreads();
  const float* Wf  = ws + OFF_WF;
  const float* cwT = ws + OFF_CWT;
  float bfu = ws[OFF_BF + d];
  float acc = conv_b[d];
#pragma unroll
  for (int k = 0; k < DC; ++k) {
    float xz = bfu;
#pragma unroll
    for (int i = 0; i < NI; ++i) xz = fmaf(scat[k][i], Wf[i * 2 * DI + d], xz);
    if (t - (DC - 1) + k < 0) xz = 0.f;   // causal zero-pad (pad is pre-bias xz)
    acc = fmaf(cwT[k * DI + d], xz, acc);
  }
  ws[OFF_U + (size_t)tlin * DI + d] = fsilu(acc);
}

// ---------------- x_proj + dt_proj fused; 8 rows/block ----------------
__global__ __launch_bounds__(256) void k_proj(
    const float* __restrict__ W_dt, const float* __restrict__ b_dt,
    float* __restrict__ ws) {
  __shared__ float su[8][DI];           // 32 KB
  __shared__ float sdbl[8][RK];
  int bid = blockIdx.x, tid = threadIdx.x;
  int r0 = bid * 8;
  const float* up = ws + OFF_U;
#pragma unroll
  for (int j = 0; j < 8; ++j) {
    int fid = tid + j * 256;            // 2048 float4 slots
    int r = fid >> 8, c4 = fid & 255;
    *(float4*)&su[r][c4 * 4] = *(const float4*)&up[((size_t)(r0 + r)) * DI + c4 * 4];
  }
  __syncthreads();
  // phase 1: x_dbl = u @ W_xproj  (each thread: 1 col x 2 rows, full K)
  const float* WxT = ws + OFF_WXT;
  int c = tid & 63, g = tid >> 6;       // rows g*2, g*2+1
  float a0 = 0.f, a1 = 0.f;
  const float* wcol = WxT + (size_t)c * DI;
#pragma unroll 4
  for (int k = 0; k < DI; ++k) {
    float w = wcol[k];
    a0 = fmaf(su[g * 2 + 0][k], w, a0);
    a1 = fmaf(su[g * 2 + 1][k], w, a1);
  }
  if (c < RK) {
    sdbl[g * 2 + 0][c] = a0;
    sdbl[g * 2 + 1][c] = a1;
  } else if (c < RK + NS) {
    int s = c - RK;
    ws[OFF_BC + ((size_t)(r0 + g * 2 + 0)) * NS + s] = a0;
    ws[OFF_BC + ((size_t)(r0 + g * 2 + 1)) * NS + s] = a1;
  } else {
    int s = c - RK - NS;
    ws[OFF_CC + ((size_t)(r0 + g * 2 + 0)) * NS + s] = a0;
    ws[OFF_CC + ((size_t)(r0 + g * 2 + 1)) * NS + s] = a1;
  }
  __syncthreads();
  // phase 2: dt = softplus(dt_lo @ W_dt + b_dt)
  float* dtp = ws + OFF_DT;
#pragma unroll
  for (int j = 0; j < 4; ++j) {
    int dd = tid + j * 256;
    float bdt = b_dt[dd];
    float wreg[RK];
#pragma unroll
    for (int r32 = 0; r32 < RK; ++r32) wreg[r32] = W_dt[r32 * DI + dd];
#pragma unroll
    for (int rr = 0; rr < 8; ++rr) {
      float a = bdt;
#pragma unroll
      for (int r32 = 0; r32 < RK; ++r32) a = fmaf(sdbl[rr][r32], wreg[r32], a);
      float sp = (a > 15.f) ? a : log1pf(__expf(a));
      dtp[((size_t)(r0 + rr)) * DI + dd] = sp;
    }
  }
}

// ---------------- selective scan ----------------
#define TCH 64
__global__ __launch_bounds__(256) void k_scan(
    const float* __restrict__ Dvec, float* __restrict__ ws) {
  __shared__ float sdt[2][TCH][NS];
  __shared__ float suu[2][TCH][NS];
  __shared__ float sBB[2][TCH][NS];
  __shared__ float sCC[2][TCH][NS];
  int bid = blockIdx.x, tid = threadIdx.x;   // 512 blocks
  int b = bid >> 6;
  int d0 = (bid & 63) << 4;
  int lane = tid & 63, w = tid >> 6;
  int s = lane & 15;
  int dloc = (w << 2) + (lane >> 4);
  int d = d0 + dloc;
  const float* dtp = ws + OFF_DT + ((size_t)b * LL) * DI + d0;
  const float* up  = ws + OFF_U  + ((size_t)b * LL) * DI + d0;
  const float* Bp  = ws + OFF_BC + ((size_t)b * LL) * NS;
  const float* Cp  = ws + OFF_CC + ((size_t)b * LL) * NS;
  float A2v = ws[OFF_A2 + (size_t)d * NS + s];
  float Dv  = Dvec[d];
  int tt = tid >> 2, q = tid & 3;
  // stage chunk 0
  float4 rdt = *(const float4*)&dtp[(size_t)tt * DI + q * 4];
  float4 ruu = *(const float4*)&up [(size_t)tt * DI + q * 4];
  float4 rbb = *(const float4*)&Bp [tt * NS + q * 4];
  float4 rcc = *(const float4*)&Cp [tt * NS + q * 4];
  *(float4*)&sdt[0][tt][q * 4] = rdt;
  *(float4*)&suu[0][tt][q * 4] = ruu;
  *(float4*)&sBB[0][tt][q * 4] = rbb;
  *(float4*)&sCC[0][tt][q * 4] = rcc;
  __syncthreads();
  float h = 0.f;
  int buf = 0;
  float* ysp = ws + OFF_YS;
  for (int ch = 0; ch < LL / TCH; ++ch) {
    int t0 = ch * TCH;
    bool has_next = (ch + 1 < LL / TCH);
    if (has_next) {                       // prefetch next chunk into regs
      int tb = t0 + TCH + tt;
      rdt = *(const float4*)&dtp[(size_t)tb * DI + q * 4];
      ruu = *(const float4*)&up [(size_t)tb * DI + q * 4];
      rbb = *(const float4*)&Bp [tb * NS + q * 4];
      rcc = *(const float4*)&Cp [tb * NS + q * 4];
    }
    if (t0 + TCH <= LL - PRED) {          // no y output needed
#pragma unroll 4
      for (int t = 0; t < TCH; ++t) {
        float dtv = sdt[buf][t][dloc];
        float uv  = suu[buf][t][dloc];
        float bv  = sBB[buf][t][s];
        float dA  = fexp2(dtv * A2v);
        h = fmaf(dA, h, dtv * bv * uv);
      }
    } else {                              // tail: also produce y
      for (int t = 0; t < TCH; ++t) {
        float dtv = sdt[buf][t][dloc];
        float uv  = suu[buf][t][dloc];
        float bv  = sBB[buf][t][s];
        float cv  = sCC[buf][t][s];
        float dA  = fexp2(dtv * A2v);
        h = fmaf(dA, h, dtv * bv * uv);
        int tg = t0 + t;
        if (tg >= LL - PRED) {
          float v = h * cv;
          v += __shfl_xor(v, 1);
          v += __shfl_xor(v, 2);
          v += __shfl_xor(v, 4);
          v += __shfl_xor(v, 8);
          if (s == 0)
            ysp[((size_t)(b * PRED + (tg - (LL - PRED)))) * DI + d] = fmaf(Dv, uv, v);
        }
      }
    }
    if (has_next) {
      int nb = buf ^ 1;
      *(float4*)&sdt[nb][tt][q * 4] = rdt;
      *(float4*)&suu[nb][tt][q * 4] = ruu;
      *(float4*)&sBB[nb][tt][q * 4] = rbb;
      *(float4*)&sCC[nb][tt][q * 4] = rcc;
      buf = nb;
    }
    __syncthreads();
  }
}

// ---------------- z-gate + fused out_proj@W_fc ----------------
__global__ __launch_bounds__(256) void k_out(
    const float* __restrict__ xe, const float* __restrict__ xm,
    const float* __restrict__ b_fc, const float* __restrict__ ws,
    float* __restrict__ out) {
  __shared__ float scat[NI];
  __shared__ float sacc[4][NC];
  int bid = blockIdx.x, tid = threadIdx.x;   // 768 blocks = B*PRED
  int b = bid / PRED, p = bid - b * PRED;
  int t = LL - PRED + p;
  if (tid < NI) scat[tid] = (tid < 7) ? xe[(size_t)(b * LL + t) * 7 + tid]
                                      : xm[(size_t)(b * LL + t) * 4 + (tid - 7)];
  __syncthreads();
  const float* Wf  = ws + OFF_WF;
  const float* bf  = ws + OFF_BF;
  const float* Wof = ws + OFF_WOF;
  const float* ysp = ws + OFF_YS + ((size_t)bid) * DI;
  float acc[NC];
#pragma unroll
  for (int cc = 0; cc < NC; ++cc) acc[cc] = 0.f;
#pragma unroll
  for (int j = 0; j < 4; ++j) {
    int dd = tid + j * 256;
    float zv = bf[DI + dd];
#pragma unroll
    for (int i = 0; i < NI; ++i) zv = fmaf(scat[i], Wf[i * 2 * DI + DI + dd], zv);
    float g = ysp[dd] * fsilu(zv);
#pragma unroll
    for (int cc = 0; cc < NC; ++cc) acc[cc] = fmaf(g, Wof[dd * NC + cc], acc[cc]);
  }
#pragma unroll
  for (int cc = 0; cc < NC; ++cc) {
    float v = acc[cc];
    for (int off = 32; off > 0; off >>= 1) v += __shfl_down(v, off);
    if ((tid & 63) == 0) sacc[tid >> 6][cc] = v;
  }
  __syncthreads();
  if (tid < NC)
    out[(size_t)bid * NC + tid] =
        sacc[0][tid] + sacc[1][tid] + sacc[2][tid] + sacc[3][tid] + b_fc[tid];
}

extern "C" void kernel_launch(void* const* d_in, const int* in_sizes, int n_in,
                              void* d_out, int out_size, void* d_ws, size_t ws_size,
                              hipStream_t stream) {
  const float* xe    = (const float*)d_in[0];
  const float* xm    = (const float*)d_in[1];
  const float* W_in  = (const float*)d_in[4];
  const float* b_in  = (const float*)d_in[5];
  const float* W_ip  = (const float*)d_in[6];
  const float* cw    = (const float*)d_in[7];
  const float* cb    = (const float*)d_in[8];
  const float* W_xp  = (const float*)d_in[9];
  const float* W_dt  = (const float*)d_in[10];
  const float* b_dt  = (const float*)d_in[11];
  const float* A_log = (const float*)d_in[12];
  const float* Dv    = (const float*)d_in[13];
  const float* W_out = (const float*)d_in[14];
  const float* W_fc  = (const float*)d_in[15];
  const float* b_fc  = (const float*)d_in[16];
  float* ws  = (float*)d_ws;
  float* out = (float*)d_out;

  k_pre <<<460, 256, 0, stream>>>(W_in, b_in, W_ip, cw, W_xp, A_log, W_out, W_fc, ws);
  k_u   <<<BB * LL * 4, 256, 0, stream>>>(xe, xm, cb, ws);
  k_proj<<<BB * LL / 8, 256, 0, stream>>>(W_dt, b_dt, ws);
  k_scan<<<BB * 64, 256, 0, stream>>>(Dv, ws);
  k_out <<<BB * PRED, 256, 0, stream>>>(xe, xm, b_fc, ws, out);
}

// Round 2
// 298.154 us; speedup vs baseline: 1.5851x; 1.5851x over previous
//
#include <hip/hip_runtime.h>
#include <math.h>

#define BB 8
#define LL 2048
#define DM 512
#define DI 1024
#define NS 16
#define DC 4
#define RK 32
#define NI 11
#define PRED 96
#define NC 7

// ws layout (float offsets)
static constexpr size_t OFF_WF  = 0;          // 11*2048 fused W_in@W_inproj
static constexpr size_t OFF_BF  = 22528;      // 2048    fused b_in@W_inproj
static constexpr size_t OFF_A2  = 24576;      // 1024*16 A * log2(e)
static constexpr size_t OFF_WOF = 40960;      // 1024*7  W_out@W_fc
static constexpr size_t OFF_CWT = 48128;      // 4*1024  conv_w transposed
static constexpr size_t OFF_U   = 117760;     // 8*2048*1024 u (post conv+silu)
static constexpr size_t OFF_DT  = 16894976;   // 8*2048*1024 dt (post softplus)
static constexpr size_t OFF_BC  = 33672192;   // 8*2048*16
static constexpr size_t OFF_CC  = 33934336;   // 8*2048*16
static constexpr size_t OFF_YS  = 34196480;   // 8*96*1024 scan y output
// total = 34982912 floats = 133.5 MB

__device__ __forceinline__ float fexp2(float x) {
#if __has_builtin(__builtin_amdgcn_exp2f)
  return __builtin_amdgcn_exp2f(x);
#else
  return exp2f(x);
#endif
}
__device__ __forceinline__ float fsilu(float x) {
  return x / (1.f + __expf(-x));
}

// ---------------- precompute fused weights ----------------
__global__ __launch_bounds__(256) void k_pre(
    const float* __restrict__ W_in, const float* __restrict__ b_in,
    const float* __restrict__ W_inproj, const float* __restrict__ conv_w,
    const float* __restrict__ A_log,
    const float* __restrict__ W_out, const float* __restrict__ W_fc,
    float* __restrict__ ws) {
  int bid = blockIdx.x, tid = threadIdx.x;
  if (bid < 96) {                       // Wf (11x2048) rows 0..10, row 11 = bf
    int idx = bid * 256 + tid;
    int r = idx >> 11, c = idx & 2047;
    float acc = 0.f;
    if (r < NI) {
      for (int k = 0; k < DM; ++k) acc = fmaf(W_in[r * DM + k], W_inproj[k * 2 * DI + c], acc);
      ws[OFF_WF + (size_t)r * 2 * DI + c] = acc;
    } else {
      for (int k = 0; k < DM; ++k) acc = fmaf(b_in[k], W_inproj[k * 2 * DI + c], acc);
      ws[OFF_BF + c] = acc;
    }
  } else if (bid < 160) {               // A2 = -exp(A_log)*log2e
    int idx = (bid - 96) * 256 + tid;   // 16384
    ws[OFF_A2 + idx] = -expf(A_log[idx]) * 1.4426950408889634f;
  } else if (bid < 188) {               // Wof = W_out @ W_fc (1024x7)
    int idx = (bid - 160) * 256 + tid;  // 7168
    int d = idx / NC, c = idx - d * NC;
    float acc = 0.f;
    for (int k = 0; k < DM; ++k) acc = fmaf(W_out[d * DM + k], W_fc[k * NC + c], acc);
    ws[OFF_WOF + idx] = acc;
  } else {                              // conv_w transpose -> [4][1024]
    int idx = (bid - 188) * 256 + tid;  // 4096
    int k = idx >> 10, d = idx & 1023;
    ws[OFF_CWT + idx] = conv_w[d * DC + k];
  }
}

// ---------------- u = silu(causal_conv(in_proj_u(cat)) + conv_b) ----------------
__global__ __launch_bounds__(256) void k_u(
    const float* __restrict__ xe, const float* __restrict__ xm,
    const float* __restrict__ conv_b, float* __restrict__ ws) {
  __shared__ float scat[DC][NI];
  int bid = blockIdx.x, tid = threadIdx.x;
  int tlin = bid >> 2;                  // b*L + t
  int b = tlin >> 11, t = tlin & (LL - 1);
  int d = ((bid & 3) << 8) + tid;
  if (tid < DC * NI) {
    int k = tid / NI, i = tid - k * NI;
    int tp = t - (DC - 1) + k;
    float v = 0.f;
    if (tp >= 0) v = (i < 7) ? xe[(size_t)(b * LL + tp) * 7 + i]
                             : xm[(size_t)(b * LL + tp) * 4 + (i - 7)];
    scat[k][i] = v;
  }
  __syncthreads();
  const float* Wf  = ws + OFF_WF;
  const float* cwT = ws + OFF_CWT;
  float wfv[NI];
#pragma unroll
  for (int i = 0; i < NI; ++i) wfv[i] = Wf[i * 2 * DI + d];
  float bfu = ws[OFF_BF + d];
  float acc = conv_b[d];
#pragma unroll
  for (int k = 0; k < DC; ++k) {
    float xz = bfu;
#pragma unroll
    for (int i = 0; i < NI; ++i) xz = fmaf(scat[k][i], wfv[i], xz);
    if (t - (DC - 1) + k < 0) xz = 0.f;   // causal zero-pad (pad is pre-bias xz)
    acc = fmaf(cwT[k * DI + d], xz, acc);
  }
  ws[OFF_U + (size_t)tlin * DI + d] = fsilu(acc);
}

// ---------------- x_proj + dt_proj fused; 64 rows/block, 512 threads ----------------
#define PR_ROWS 64
__global__ __launch_bounds__(512) void k_proj(
    const float* __restrict__ W_xproj, const float* __restrict__ W_dt,
    const float* __restrict__ b_dt, float* __restrict__ ws) {
  __shared__ float sdbl[PR_ROWS][RK];       // 8 KB
  int bid = blockIdx.x, tid = threadIdx.x;  // 256 blocks
  int r0 = bid * PR_ROWS;
  // ---- phase 1: x_dbl = u @ W_xproj (rows 16384, cols 64, K 1024)
  int c4 = tid & 15;            // col group: cols c4*4 .. c4*4+3
  int rg = tid >> 4;            // 0..31 -> rows rg*2, rg*2+1
  const float* up = ws + OFF_U + (size_t)(r0 + rg * 2) * DI;
  const float* wp = W_xproj + c4 * 4;
  float a00 = 0.f, a01 = 0.f, a02 = 0.f, a03 = 0.f;
  float a10 = 0.f, a11 = 0.f, a12 = 0.f, a13 = 0.f;
  for (int k4 = 0; k4 < DI / 4; ++k4) {
    float uf0[4], uf1[4];
    *(float4*)uf0 = *(const float4*)&up[k4 * 4];
    *(float4*)uf1 = *(const float4*)&up[DI + k4 * 4];
#pragma unroll
    for (int kk = 0; kk < 4; ++kk) {
      float4 wv = *(const float4*)&wp[(size_t)(k4 * 4 + kk) * 64];
      float e0 = uf0[kk], e1 = uf1[kk];
      a00 = fmaf(e0, wv.x, a00); a01 = fmaf(e0, wv.y, a01);
      a02 = fmaf(e0, wv.z, a02); a03 = fmaf(e0, wv.w, a03);
      a10 = fmaf(e1, wv.x, a10); a11 = fmaf(e1, wv.y, a11);
      a12 = fmaf(e1, wv.z, a12); a13 = fmaf(e1, wv.w, a13);
    }
  }
  int row0 = rg * 2, row1 = rg * 2 + 1;
  if (c4 < 8) {                           // dt_lo cols 0..31 -> LDS
    float4 v0 = {a00, a01, a02, a03}, v1 = {a10, a11, a12, a13};
    *(float4*)&sdbl[row0][c4 * 4] = v0;
    *(float4*)&sdbl[row1][c4 * 4] = v1;
  } else if (c4 < 12) {                   // B cols 32..47
    float4 v0 = {a00, a01, a02, a03}, v1 = {a10, a11, a12, a13};
    *(float4*)&ws[OFF_BC + (size_t)(r0 + row0) * NS + (c4 - 8) * 4] = v0;
    *(float4*)&ws[OFF_BC + (size_t)(r0 + row1) * NS + (c4 - 8) * 4] = v1;
  } else {                                // C cols 48..63
    float4 v0 = {a00, a01, a02, a03}, v1 = {a10, a11, a12, a13};
    *(float4*)&ws[OFF_CC + (size_t)(r0 + row0) * NS + (c4 - 12) * 4] = v0;
    *(float4*)&ws[OFF_CC + (size_t)(r0 + row1) * NS + (c4 - 12) * 4] = v1;
  }
  __syncthreads();
  // ---- phase 2: dt = softplus(dt_lo @ W_dt + b_dt); thread owns cols tid, tid+512
  float w0[RK], w1[RK];
#pragma unroll
  for (int r = 0; r < RK; ++r) {
    w0[r] = W_dt[r * DI + tid];
    w1[r] = W_dt[r * DI + tid + 512];
  }
  float b0 = b_dt[tid], b1 = b_dt[tid + 512];
  float* dtp = ws + OFF_DT;
  for (int row = 0; row < PR_ROWS; ++row) {
    float sv[RK];
#pragma unroll
    for (int q = 0; q < RK / 4; ++q)
      *(float4*)&sv[q * 4] = *(const float4*)&sdbl[row][q * 4];
    float acc0 = b0, acc1 = b1;
#pragma unroll
    for (int r = 0; r < RK; ++r) {
      acc0 = fmaf(sv[r], w0[r], acc0);
      acc1 = fmaf(sv[r], w1[r], acc1);
    }
    float sp0 = (acc0 > 15.f) ? acc0 : __logf(1.f + __expf(acc0));
    float sp1 = (acc1 > 15.f) ? acc1 : __logf(1.f + __expf(acc1));
    dtp[(size_t)(r0 + row) * DI + tid] = sp0;
    dtp[(size_t)(r0 + row) * DI + tid + 512] = sp1;
  }
}

// ---------------- selective scan ----------------
#define TCH 64
__global__ __launch_bounds__(256) void k_scan(
    const float* __restrict__ Dvec, float* __restrict__ ws) {
  __shared__ float sdt[2][TCH][NS];
  __shared__ float suu[2][TCH][NS];
  __shared__ float sBB[2][TCH][NS];
  __shared__ float sCC[2][TCH][NS];
  int bid = blockIdx.x, tid = threadIdx.x;   // 512 blocks
  int b = bid >> 6;
  int d0 = (bid & 63) << 4;
  int lane = tid & 63, w = tid >> 6;
  int s = lane & 15;
  int dloc = (w << 2) + (lane >> 4);
  int d = d0 + dloc;
  const float* dtp = ws + OFF_DT + ((size_t)b * LL) * DI + d0;
  const float* up  = ws + OFF_U  + ((size_t)b * LL) * DI + d0;
  const float* Bp  = ws + OFF_BC + ((size_t)b * LL) * NS;
  const float* Cp  = ws + OFF_CC + ((size_t)b * LL) * NS;
  float A2v = ws[OFF_A2 + (size_t)d * NS + s];
  float Dv  = Dvec[d];
  int tt = tid >> 2, q = tid & 3;
  // stage chunk 0
  float4 rdt = *(const float4*)&dtp[(size_t)tt * DI + q * 4];
  float4 ruu = *(const float4*)&up [(size_t)tt * DI + q * 4];
  float4 rbb = *(const float4*)&Bp [tt * NS + q * 4];
  float4 rcc = *(const float4*)&Cp [tt * NS + q * 4];
  *(float4*)&sdt[0][tt][q * 4] = rdt;
  *(float4*)&suu[0][tt][q * 4] = ruu;
  *(float4*)&sBB[0][tt][q * 4] = rbb;
  *(float4*)&sCC[0][tt][q * 4] = rcc;
  __syncthreads();
  float h = 0.f;
  int buf = 0;
  float* ysp = ws + OFF_YS;
  for (int ch = 0; ch < LL / TCH; ++ch) {
    int t0 = ch * TCH;
    bool has_next = (ch + 1 < LL / TCH);
    if (has_next) {                       // prefetch next chunk into regs
      int tb = t0 + TCH + tt;
      rdt = *(const float4*)&dtp[(size_t)tb * DI + q * 4];
      ruu = *(const float4*)&up [(size_t)tb * DI + q * 4];
      rbb = *(const float4*)&Bp [tb * NS + q * 4];
      rcc = *(const float4*)&Cp [tb * NS + q * 4];
    }
    if (t0 + TCH <= LL - PRED) {          // no y output needed
#pragma unroll 4
      for (int t = 0; t < TCH; ++t) {
        float dtv = sdt[buf][t][dloc];
        float uv  = suu[buf][t][dloc];
        float bv  = sBB[buf][t][s];
        float dA  = fexp2(dtv * A2v);
        h = fmaf(dA, h, dtv * bv * uv);
      }
    } else {                              // tail: also produce y
      for (int t = 0; t < TCH; ++t) {
        float dtv = sdt[buf][t][dloc];
        float uv  = suu[buf][t][dloc];
        float bv  = sBB[buf][t][s];
        float cv  = sCC[buf][t][s];
        float dA  = fexp2(dtv * A2v);
        h = fmaf(dA, h, dtv * bv * uv);
        int tg = t0 + t;
        if (tg >= LL - PRED) {
          float v = h * cv;
          v += __shfl_xor(v, 1);
          v += __shfl_xor(v, 2);
          v += __shfl_xor(v, 4);
          v += __shfl_xor(v, 8);
          if (s == 0)
            ysp[((size_t)(b * PRED + (tg - (LL - PRED)))) * DI + d] = fmaf(Dv, uv, v);
        }
      }
    }
    if (has_next) {
      int nb = buf ^ 1;
      *(float4*)&sdt[nb][tt][q * 4] = rdt;
      *(float4*)&suu[nb][tt][q * 4] = ruu;
      *(float4*)&sBB[nb][tt][q * 4] = rbb;
      *(float4*)&sCC[nb][tt][q * 4] = rcc;
      buf = nb;
    }
    __syncthreads();
  }
}

// ---------------- z-gate + fused out_proj@W_fc ----------------
__global__ __launch_bounds__(256) void k_out(
    const float* __restrict__ xe, const float* __restrict__ xm,
    const float* __restrict__ b_fc, const float* __restrict__ ws,
    float* __restrict__ out) {
  __shared__ float scat[NI];
  __shared__ float sacc[4][NC];
  int bid = blockIdx.x, tid = threadIdx.x;   // 768 blocks = B*PRED
  int b = bid / PRED, p = bid - b * PRED;
  int t = LL - PRED + p;
  if (tid < NI) scat[tid] = (tid < 7) ? xe[(size_t)(b * LL + t) * 7 + tid]
                                      : xm[(size_t)(b * LL + t) * 4 + (tid - 7)];
  __syncthreads();
  const float* Wf  = ws + OFF_WF;
  const float* bf  = ws + OFF_BF;
  const float* Wof = ws + OFF_WOF;
  const float* ysp = ws + OFF_YS + ((size_t)bid) * DI;
  float acc[NC];
#pragma unroll
  for (int cc = 0; cc < NC; ++cc) acc[cc] = 0.f;
#pragma unroll
  for (int j = 0; j < 4; ++j) {
    int dd = tid + j * 256;
    float zv = bf[DI + dd];
#pragma unroll
    for (int i = 0; i < NI; ++i) zv = fmaf(scat[i], Wf[i * 2 * DI + DI + dd], zv);
    float g = ysp[dd] * fsilu(zv);
#pragma unroll
    for (int cc = 0; cc < NC; ++cc) acc[cc] = fmaf(g, Wof[dd * NC + cc], acc[cc]);
  }
#pragma unroll
  for (int cc = 0; cc < NC; ++cc) {
    float v = acc[cc];
    for (int off = 32; off > 0; off >>= 1) v += __shfl_down(v, off);
    if ((tid & 63) == 0) sacc[tid >> 6][cc] = v;
  }
  __syncthreads();
  if (tid < NC)
    out[(size_t)bid * NC + tid] =
        sacc[0][tid] + sacc[1][tid] + sacc[2][tid] + sacc[3][tid] + b_fc[tid];
}

extern "C" void kernel_launch(void* const* d_in, const int* in_sizes, int n_in,
                              void* d_out, int out_size, void* d_ws, size_t ws_size,
                              hipStream_t stream) {
  const float* xe    = (const float*)d_in[0];
  const float* xm    = (const float*)d_in[1];
  const float* W_in  = (const float*)d_in[4];
  const float* b_in  = (const float*)d_in[5];
  const float* W_ip  = (const float*)d_in[6];
  const float* cw    = (const float*)d_in[7];
  const float* cb    = (const float*)d_in[8];
  const float* W_xp  = (const float*)d_in[9];
  const float* W_dt  = (const float*)d_in[10];
  const float* b_dt  = (const float*)d_in[11];
  const float* A_log = (const float*)d_in[12];
  const float* Dv    = (const float*)d_in[13];
  const float* W_out = (const float*)d_in[14];
  const float* W_fc  = (const float*)d_in[15];
  const float* b_fc  = (const float*)d_in[16];
  float* ws  = (float*)d_ws;
  float* out = (float*)d_out;

  k_pre <<<204, 256, 0, stream>>>(W_in, b_in, W_ip, cw, A_log, W_out, W_fc, ws);
  k_u   <<<BB * LL * 4, 256, 0, stream>>>(xe, xm, cb, ws);
  k_proj<<<BB * LL / PR_ROWS, 512, 0, stream>>>(W_xp, W_dt, b_dt, ws);
  k_scan<<<BB * 64, 256, 0, stream>>>(Dv, ws);
  k_out <<<BB * PRED, 256, 0, stream>>>(xe, xm, b_fc, ws, out);
}

// Round 3
// 195.790 us; speedup vs baseline: 2.4138x; 1.5228x over previous
//
#include <hip/hip_runtime.h>
#include <math.h>

#define BB 8
#define LL 2048
#define DI 1024
#define NS 16
#define RK 32
#define NI 11
#define PRED 96
#define NC 7

// ws layout (float offsets)
static constexpr size_t OFF_WF  = 0;        // 11x2048 f32 fused W_in@W_inproj
static constexpr size_t OFF_BF  = 22528;    // 2048 f32 fused b_in@W_inproj
static constexpr size_t OFF_A2  = 24576;    // 1024x16 f32  -exp(A_log)*log2e
static constexpr size_t OFF_WOF = 40960;    // 1024x7 f32 W_out@W_fc
static constexpr size_t OFF_CWT = 48128;    // 4x1024 f32 conv_w^T
static constexpr size_t OFF_WXH = 52224;    // 64x1024 bf16 W_xproj^T (32768 f32 slots)
static constexpr size_t OFF_DL  = 84992;    // 16384x32 f32 dt_lo (raw)
static constexpr size_t OFF_BC  = 609280;   // 16384x16 f32 B
static constexpr size_t OFF_CC  = 740352;   // 16384x16 f32 C
static constexpr size_t OFF_YS  = 871424;   // 8x96x1024 f32 scan y
static constexpr size_t OFF_UH  = 1657856;  // 16384x1024 bf16 u (8388608 f32 slots)
static constexpr size_t OFF_SA  = OFF_UH;           // k_pre scratch (reused before k_u)
static constexpr size_t OFF_SC  = OFF_UH + 196608;

typedef __attribute__((ext_vector_type(8))) __bf16 bf16x8;
typedef __attribute__((ext_vector_type(4))) float f32x4;

__device__ __forceinline__ float fexp2(float x) {
#if __has_builtin(__builtin_amdgcn_exp2f)
  return __builtin_amdgcn_exp2f(x);
#else
  return exp2f(x);
#endif
}
__device__ __forceinline__ unsigned short f2bf(float f) {
  unsigned int b = __float_as_uint(f);
  unsigned int r = (b + 0x7fffu + ((b >> 16) & 1u)) >> 16;
  return (unsigned short)r;
}
__device__ __forceinline__ float bflo(unsigned int u) { return __uint_as_float(u << 16); }
__device__ __forceinline__ float bfhi(unsigned int u) { return __uint_as_float(u & 0xffff0000u); }
__device__ __forceinline__ float softp(float a) {
  return (a > 15.f) ? a : __logf(1.f + __expf(a));
}

// ---------------- precompute, K-split partials ----------------
__global__ __launch_bounds__(256) void k_pre1(
    const float* __restrict__ W_in, const float* __restrict__ b_in,
    const float* __restrict__ W_inproj, const float* __restrict__ conv_w,
    const float* __restrict__ W_xproj, const float* __restrict__ A_log,
    const float* __restrict__ W_out, const float* __restrict__ W_fc,
    float* __restrict__ ws) {
  int bid = blockIdx.x, tid = threadIdx.x;
  if (bid < 768) {                       // Wf partials: 12x2048 out, K-split 8
    int ks = bid / 96;
    int out = (bid % 96) * 256 + tid;
    int r = out >> 11, c = out & 2047;
    int k0 = ks * 64;
    float acc = 0.f;
    for (int k = 0; k < 64; ++k) {
      float a = (r < NI) ? W_in[r * 512 + k0 + k] : b_in[k0 + k];
      acc = fmaf(a, W_inproj[(size_t)(k0 + k) * 2048 + c], acc);
    }
    ws[OFF_SA + (size_t)ks * 24576 + out] = acc;
  } else if (bid < 832) {                // A2
    int idx = (bid - 768) * 256 + tid;
    ws[OFF_A2 + idx] = -expf(A_log[idx]) * 1.4426950408889634f;
  } else if (bid < 1056) {               // Wof partials: 1024x7, K-split 8
    int lb = bid - 832;
    int ks = lb / 28;
    int out = (lb % 28) * 256 + tid;
    int d = out / NC, cc = out - d * NC;
    int k0 = ks * 64;
    float acc = 0.f;
    for (int k = 0; k < 64; ++k)
      acc = fmaf(W_out[d * 512 + k0 + k], W_fc[(k0 + k) * NC + cc], acc);
    ws[OFF_SC + (size_t)ks * 7168 + out] = acc;
  } else if (bid < 1072) {               // conv_w^T
    int idx = (bid - 1056) * 256 + tid;
    int k = idx >> 10, dd = idx & 1023;
    ws[OFF_CWT + idx] = conv_w[dd * 4 + k];
  } else {                               // W_xproj^T -> bf16 [64 cols][1024 k]
    int idx = (bid - 1072) * 256 + tid;  // 65536
    int c = idx >> 10, k = idx & 1023;
    unsigned short* wxh = (unsigned short*)(ws + OFF_WXH);
    wxh[idx] = f2bf(W_xproj[(size_t)k * 64 + c]);
  }
}

__global__ __launch_bounds__(256) void k_pre2(float* __restrict__ ws) {
  int idx = blockIdx.x * 256 + threadIdx.x;  // 31744 total
  if (idx < 24576) {
    float acc = 0.f;
    for (int ks = 0; ks < 8; ++ks) acc += ws[OFF_SA + (size_t)ks * 24576 + idx];
    int r = idx >> 11, c = idx & 2047;
    if (r < NI) ws[OFF_WF + (size_t)r * 2048 + c] = acc;
    else ws[OFF_BF + c] = acc;
  } else {
    int i2 = idx - 24576;
    float acc = 0.f;
    for (int ks = 0; ks < 8; ++ks) acc += ws[OFF_SC + (size_t)ks * 7168 + i2];
    ws[OFF_WOF + i2] = acc;
  }
}

// ---------------- u = silu(conv(in_proj_u)) -> bf16; 8 t per block ----------------
__global__ __launch_bounds__(256) void k_u(
    const float* __restrict__ xe, const float* __restrict__ xm,
    const float* __restrict__ conv_b, float* __restrict__ ws) {
  __shared__ float scat[11][11];
  int bid = blockIdx.x, tid = threadIdx.x;
  int tg = bid >> 2, dq = bid & 3;
  int d = dq * 256 + tid;
  int b = tg >> 8;
  int t0 = (tg & 255) * 8;
  if (tid < 121) {
    int k = tid / 11, i = tid - k * 11;
    int tp = t0 - 3 + k;
    float v = 0.f;
    if (tp >= 0) v = (i < 7) ? xe[(size_t)(b * LL + tp) * 7 + i]
                             : xm[(size_t)(b * LL + tp) * 4 + (i - 7)];
    scat[k][i] = v;
  }
  __syncthreads();
  float wfv[NI];
#pragma unroll
  for (int i = 0; i < NI; ++i) wfv[i] = ws[OFF_WF + (size_t)i * 2048 + d];
  float bfu = ws[OFF_BF + d];
  float cwv[4];
#pragma unroll
  for (int k = 0; k < 4; ++k) cwv[k] = ws[OFF_CWT + k * 1024 + d];
  float cbv = conv_b[d];
  float xzv[11];
#pragma unroll
  for (int w2 = 0; w2 < 11; ++w2) {
    int tp = t0 - 3 + w2;
    float xz = bfu;
#pragma unroll
    for (int i = 0; i < NI; ++i) xz = fmaf(scat[w2][i], wfv[i], xz);
    xzv[w2] = (tp >= 0) ? xz : 0.f;
  }
  unsigned short* uhp = (unsigned short*)(ws + OFF_UH);
#pragma unroll
  for (int tt = 0; tt < 8; ++tt) {
    float acc = cbv;
#pragma unroll
    for (int k = 0; k < 4; ++k) acc = fmaf(cwv[k], xzv[tt + k], acc);
    float uval = acc / (1.f + __expf(-acc));
    uhp[(size_t)(b * LL + t0 + tt) * DI + d] = f2bf(uval);
  }
}

// ---------------- x_proj GEMM via bf16 MFMA: 16384x64x1024 ----------------
__global__ __launch_bounds__(256) void k_proj(float* __restrict__ ws) {
  __shared__ unsigned short su[64][72];   // u tile   [row][k]
  __shared__ unsigned short sw[64][72];   // WxT tile [col][k]
  const unsigned short* uh  = (const unsigned short*)(ws + OFF_UH);
  const unsigned short* wxh = (const unsigned short*)(ws + OFF_WXH);
  int bid = blockIdx.x, tid = threadIdx.x;
  int r0 = bid * 64;
  int lane = tid & 63, w = tid >> 6;
  int srow = tid >> 3, skg = tid & 7;     // staging: 32 rows x 8 kgroups
  uint4 ru[2][2], rw[2][2];
  const ushort* ub0 = uh + (size_t)(r0 + srow) * DI + skg * 8;
  const ushort* wb0 = wxh + (size_t)srow * DI + skg * 8;
  ru[0][0] = *(const uint4*)(ub0);
  ru[0][1] = *(const uint4*)(ub0 + (size_t)32 * DI);
  rw[0][0] = *(const uint4*)(wb0);
  rw[0][1] = *(const uint4*)(wb0 + (size_t)32 * DI);
  ru[1][0] = *(const uint4*)(ub0 + 64);
  ru[1][1] = *(const uint4*)(ub0 + (size_t)32 * DI + 64);
  rw[1][0] = *(const uint4*)(wb0 + 64);
  rw[1][1] = *(const uint4*)(wb0 + (size_t)32 * DI + 64);
  f32x4 acc[4];
#pragma unroll
  for (int i = 0; i < 4; ++i) acc[i] = (f32x4){0.f, 0.f, 0.f, 0.f};
  int arow = w * 16 + (lane & 15);
  for (int kt = 0; kt < 16; ++kt) {
    int set = kt & 1;
    __syncthreads();
    *(uint4*)&su[srow][skg * 8]      = ru[set][0];
    *(uint4*)&su[srow + 32][skg * 8] = ru[set][1];
    *(uint4*)&sw[srow][skg * 8]      = rw[set][0];
    *(uint4*)&sw[srow + 32][skg * 8] = rw[set][1];
    __syncthreads();
    if (kt + 2 < 16) {
      int ko = (kt + 2) * 64;
      ru[set][0] = *(const uint4*)(ub0 + ko);
      ru[set][1] = *(const uint4*)(ub0 + (size_t)32 * DI + ko);
      rw[set][0] = *(const uint4*)(wb0 + ko);
      rw[set][1] = *(const uint4*)(wb0 + (size_t)32 * DI + ko);
    }
#pragma unroll
    for (int ks = 0; ks < 2; ++ks) {
      int koff = ks * 32 + (lane >> 4) * 8;
      bf16x8 av = *(const bf16x8*)&su[arow][koff];
#pragma unroll
      for (int nt = 0; nt < 4; ++nt) {
        bf16x8 bv = *(const bf16x8*)&sw[nt * 16 + (lane & 15)][koff];
        acc[nt] = __builtin_amdgcn_mfma_f32_16x16x32_bf16(av, bv, acc[nt], 0, 0, 0);
      }
    }
  }
  int orow = r0 + w * 16 + ((lane >> 4) << 2);
  int ocol = lane & 15;
#pragma unroll
  for (int reg = 0; reg < 4; ++reg) {
    size_t rr = orow + reg;
    ws[OFF_DL + rr * RK + ocol]      = acc[0][reg];
    ws[OFF_DL + rr * RK + 16 + ocol] = acc[1][reg];
    ws[OFF_BC + rr * NS + ocol]      = acc[2][reg];
    ws[OFF_CC + rr * NS + ocol]      = acc[3][reg];
  }
}

// ---------------- selective scan with fused dt_proj ----------------
#define TCH 64
__global__ __launch_bounds__(256) void k_scan(
    const float* __restrict__ Dvec, const float* __restrict__ W_dt,
    const float* __restrict__ b_dt, float* __restrict__ ws) {
  __shared__ float sdl[2][TCH][36];
  __shared__ float sdt[2][TCH][20];
  __shared__ float suu[2][TCH][20];
  __shared__ float sBB[2][TCH][NS];
  __shared__ float sCC[2][TCH][NS];
  int bid = blockIdx.x, tid = threadIdx.x;
  int b = bid >> 6;
  int d0 = (bid & 63) << 4;
  int lane = tid & 63, w = tid >> 6;
  int s = lane & 15;
  int dloc = (w << 2) + (lane >> 4);
  int d = d0 + dloc;
  const unsigned short* uh = (const unsigned short*)(ws + OFF_UH) + (size_t)b * LL * DI + d0;
  const float* dlp = ws + OFF_DL + (size_t)b * LL * RK;
  const float* Bp  = ws + OFF_BC + (size_t)b * LL * NS;
  const float* Cp  = ws + OFF_CC + (size_t)b * LL * NS;
  float A2v = ws[OFF_A2 + (size_t)d * NS + s];
  float Dv  = Dvec[d];
  // dt-proj role: thread computes dt for column d0+dtd at 4 t's
  int dtd = tid & 15, dts = tid >> 4;
  float wreg[RK];
#pragma unroll
  for (int k = 0; k < RK; ++k) wreg[k] = W_dt[(size_t)k * DI + d0 + dtd];
  float bdtv = b_dt[d0 + dtd];
  // staging roles
  int ut = tid >> 1, uq = tid & 1;
  int dlt = tid >> 3, dlq = tid & 7;
  int bt = tid >> 2, bq = tid & 3;
  // stage chunk 0
  if (tid < 128) {
    uint4 v = *(const uint4*)(uh + (size_t)ut * DI + uq * 8);
    float4 f0 = {bflo(v.x), bfhi(v.x), bflo(v.y), bfhi(v.y)};
    float4 f1 = {bflo(v.z), bfhi(v.z), bflo(v.w), bfhi(v.w)};
    *(float4*)&suu[0][ut][uq * 8]     = f0;
    *(float4*)&suu[0][ut][uq * 8 + 4] = f1;
  }
  *(float4*)&sdl[0][dlt][dlq * 4]      = *(const float4*)&dlp[(size_t)dlt * RK + dlq * 4];
  *(float4*)&sdl[0][dlt + 32][dlq * 4] = *(const float4*)&dlp[(size_t)(dlt + 32) * RK + dlq * 4];
  *(float4*)&sBB[0][bt][bq * 4] = *(const float4*)&Bp[(size_t)bt * NS + bq * 4];
  *(float4*)&sCC[0][bt][bq * 4] = *(const float4*)&Cp[(size_t)bt * NS + bq * 4];
  __syncthreads();
#pragma unroll
  for (int j = 0; j < 4; ++j) {
    int t = dts * 4 + j;
    float acc = bdtv;
#pragma unroll
    for (int k4 = 0; k4 < 8; ++k4) {
      float4 vv = *(const float4*)&sdl[0][t][k4 * 4];
      acc = fmaf(vv.x, wreg[k4 * 4 + 0], acc);
      acc = fmaf(vv.y, wreg[k4 * 4 + 1], acc);
      acc = fmaf(vv.z, wreg[k4 * 4 + 2], acc);
      acc = fmaf(vv.w, wreg[k4 * 4 + 3], acc);
    }
    sdt[0][t][dtd] = softp(acc);
  }
  __syncthreads();
  float h = 0.f;
  int buf = 0;
  float* ysp = ws + OFF_YS;
  for (int ch = 0; ch < LL / TCH; ++ch) {
    int t0 = ch * TCH;
    bool has_next = (ch + 1 < LL / TCH);
    uint4 ruh; float4 rdl0, rdl1, rbb, rcc;
    if (has_next) {
      int tb = t0 + TCH;
      if (tid < 128) ruh = *(const uint4*)(uh + (size_t)(tb + ut) * DI + uq * 8);
      rdl0 = *(const float4*)&dlp[(size_t)(tb + dlt) * RK + dlq * 4];
      rdl1 = *(const float4*)&dlp[(size_t)(tb + dlt + 32) * RK + dlq * 4];
      rbb  = *(const float4*)&Bp[(size_t)(tb + bt) * NS + bq * 4];
      rcc  = *(const float4*)&Cp[(size_t)(tb + bt) * NS + bq * 4];
    }
    if (t0 + TCH <= LL - PRED) {
#pragma unroll 4
      for (int t = 0; t < TCH; ++t) {
        float dtv = sdt[buf][t][dloc];
        float uv  = suu[buf][t][dloc];
        float bv  = sBB[buf][t][s];
        float dA  = fexp2(dtv * A2v);
        h = fmaf(dA, h, dtv * bv * uv);
      }
    } else {
      for (int t = 0; t < TCH; ++t) {
        float dtv = sdt[buf][t][dloc];
        float uv  = suu[buf][t][dloc];
        float bv  = sBB[buf][t][s];
        float cv  = sCC[buf][t][s];
        float dA  = fexp2(dtv * A2v);
        h = fmaf(dA, h, dtv * bv * uv);
        int tg2 = t0 + t;
        if (tg2 >= LL - PRED) {
          float v = h * cv;
          v += __shfl_xor(v, 1);
          v += __shfl_xor(v, 2);
          v += __shfl_xor(v, 4);
          v += __shfl_xor(v, 8);
          if (s == 0)
            ysp[((size_t)(b * PRED + (tg2 - (LL - PRED)))) * DI + d] = fmaf(Dv, uv, v);
        }
      }
    }
    if (has_next) {
      int nb = buf ^ 1;
      if (tid < 128) {
        float4 f0 = {bflo(ruh.x), bfhi(ruh.x), bflo(ruh.y), bfhi(ruh.y)};
        float4 f1 = {bflo(ruh.z), bfhi(ruh.z), bflo(ruh.w), bfhi(ruh.w)};
        *(float4*)&suu[nb][ut][uq * 8]     = f0;
        *(float4*)&suu[nb][ut][uq * 8 + 4] = f1;
      }
      *(float4*)&sdl[nb][dlt][dlq * 4]      = rdl0;
      *(float4*)&sdl[nb][dlt + 32][dlq * 4] = rdl1;
      *(float4*)&sBB[nb][bt][bq * 4] = rbb;
      *(float4*)&sCC[nb][bt][bq * 4] = rcc;
      __syncthreads();
#pragma unroll
      for (int j = 0; j < 4; ++j) {
        int t = dts * 4 + j;
        float acc = bdtv;
#pragma unroll
        for (int k4 = 0; k4 < 8; ++k4) {
          float4 vv = *(const float4*)&sdl[nb][t][k4 * 4];
          acc = fmaf(vv.x, wreg[k4 * 4 + 0], acc);
          acc = fmaf(vv.y, wreg[k4 * 4 + 1], acc);
          acc = fmaf(vv.z, wreg[k4 * 4 + 2], acc);
          acc = fmaf(vv.w, wreg[k4 * 4 + 3], acc);
        }
        sdt[nb][t][dtd] = softp(acc);
      }
      __syncthreads();
      buf = nb;
    }
  }
}

// ---------------- z-gate + fused out_proj@W_fc ----------------
__global__ __launch_bounds__(256) void k_out(
    const float* __restrict__ xe, const float* __restrict__ xm,
    const float* __restrict__ b_fc, const float* __restrict__ ws,
    float* __restrict__ out) {
  __shared__ float scat[NI];
  __shared__ float sacc[4][NC];
  int bid = blockIdx.x, tid = threadIdx.x;
  int b = bid / PRED, p = bid - b * PRED;
  int t = LL - PRED + p;
  if (tid < NI) scat[tid] = (tid < 7) ? xe[(size_t)(b * LL + t) * 7 + tid]
                                      : xm[(size_t)(b * LL + t) * 4 + (tid - 7)];
  __syncthreads();
  const float* Wf  = ws + OFF_WF;
  const float* bf  = ws + OFF_BF;
  const float* Wof = ws + OFF_WOF;
  const float* ysp = ws + OFF_YS + ((size_t)bid) * DI;
  float acc[NC];
#pragma unroll
  for (int cc = 0; cc < NC; ++cc) acc[cc] = 0.f;
#pragma unroll
  for (int j = 0; j < 4; ++j) {
    int dd = tid + j * 256;
    float zv = bf[DI + dd];
#pragma unroll
    for (int i = 0; i < NI; ++i) zv = fmaf(scat[i], Wf[(size_t)i * 2048 + DI + dd], zv);
    float g = ysp[dd] * (zv / (1.f + __expf(-zv)));
#pragma unroll
    for (int cc = 0; cc < NC; ++cc) acc[cc] = fmaf(g, Wof[dd * NC + cc], acc[cc]);
  }
#pragma unroll
  for (int cc = 0; cc < NC; ++cc) {
    float v = acc[cc];
    for (int off = 32; off > 0; off >>= 1) v += __shfl_down(v, off);
    if ((tid & 63) == 0) sacc[tid >> 6][cc] = v;
  }
  __syncthreads();
  if (tid < NC)
    out[(size_t)bid * NC + tid] =
        sacc[0][tid] + sacc[1][tid] + sacc[2][tid] + sacc[3][tid] + b_fc[tid];
}

extern "C" void kernel_launch(void* const* d_in, const int* in_sizes, int n_in,
                              void* d_out, int out_size, void* d_ws, size_t ws_size,
                              hipStream_t stream) {
  const float* xe    = (const float*)d_in[0];
  const float* xm    = (const float*)d_in[1];
  const float* W_in  = (const float*)d_in[4];
  const float* b_in  = (const float*)d_in[5];
  const float* W_ip  = (const float*)d_in[6];
  const float* cw    = (const float*)d_in[7];
  const float* cb    = (const float*)d_in[8];
  const float* W_xp  = (const float*)d_in[9];
  const float* W_dt  = (const float*)d_in[10];
  const float* b_dt  = (const float*)d_in[11];
  const float* A_log = (const float*)d_in[12];
  const float* Dv    = (const float*)d_in[13];
  const float* W_out = (const float*)d_in[14];
  const float* W_fc  = (const float*)d_in[15];
  const float* b_fc  = (const float*)d_in[16];
  float* ws  = (float*)d_ws;
  float* out = (float*)d_out;

  k_pre1<<<1328, 256, 0, stream>>>(W_in, b_in, W_ip, cw, W_xp, A_log, W_out, W_fc, ws);
  k_pre2<<<124, 256, 0, stream>>>(ws);
  k_u   <<<8192, 256, 0, stream>>>(xe, xm, cb, ws);
  k_proj<<<256, 256, 0, stream>>>(ws);
  k_scan<<<512, 256, 0, stream>>>(Dv, W_dt, b_dt, ws);
  k_out <<<BB * PRED, 256, 0, stream>>>(xe, xm, b_fc, ws, out);
}

// Round 5
// 168.530 us; speedup vs baseline: 2.8042x; 1.1618x over previous
//
#include <hip/hip_runtime.h>
#include <math.h>

#define BB 8
#define LL 2048
#define DI 1024
#define NS 16
#define RK 32
#define NI 11
#define PRED 96
#define NC 7

// ws layout (float offsets)
static constexpr size_t OFF_WF   = 0;         // 11x2048 f32 fused W_in@W_inproj
static constexpr size_t OFF_BF   = 22528;     // 2048 f32
static constexpr size_t OFF_A2   = 24576;     // 1024x16 f32  -exp(A_log)*log2e
static constexpr size_t OFF_WOF  = 40960;     // 1024x7 f32 W_out@W_fc
static constexpr size_t OFF_CWT  = 48128;     // 4x1024 f32 conv_w^T
static constexpr size_t OFF_WXH  = 52224;     // 64x1024 bf16 W_xproj^T
static constexpr size_t OFF_WDTH = 84992;     // 1024x32 f16 W_dt^T
static constexpr size_t OFF_DLH  = 101376;    // 16384x32 f16 dt_lo
static constexpr size_t OFF_BC   = 363520;    // 16384x16 f32 B
static constexpr size_t OFF_CC   = 625664;    // 16384x16 f32 C
static constexpr size_t OFF_YS   = 887808;    // 8x96x1024 f32 scan y
static constexpr size_t OFF_PB   = 1674240;   // [8][32][1024][16] f32 chunk decay
static constexpr size_t OFF_HB   = 5868544;   // [8][32][1024][16] f32 chunk local h
static constexpr size_t OFF_H30  = 10062848;  // [8][1024][16] f32 h entering ch30
static constexpr size_t OFF_H31  = 10193920;  // [8][1024][16] f32 h entering ch31
static constexpr size_t OFF_UH   = 10324992;  // 16384x1024 bf16 u
static constexpr size_t OFF_DTH  = 18713600;  // 16384x1024 f16 dt
// end 27102208 f32 = 108.4 MB
static constexpr size_t OFF_SA   = OFF_UH;    // k_pre scratch (before k_u)
static constexpr size_t OFF_SC   = OFF_UH + 196608;

typedef __attribute__((ext_vector_type(8))) __bf16 bf16x8;
typedef __attribute__((ext_vector_type(8))) _Float16 f16x8;
typedef __attribute__((ext_vector_type(4))) float f32x4;

__device__ __forceinline__ float fexp2(float x) {
#if __has_builtin(__builtin_amdgcn_exp2f)
  return __builtin_amdgcn_exp2f(x);
#else
  return exp2f(x);
#endif
}
__device__ __forceinline__ unsigned short f2bf(float f) {
  unsigned int b = __float_as_uint(f);
  unsigned int r = (b + 0x7fffu + ((b >> 16) & 1u)) >> 16;
  return (unsigned short)r;
}
__device__ __forceinline__ unsigned short f2h_u(float f) {
  union { _Float16 h; unsigned short u; } c;
  c.h = (_Float16)f;
  return c.u;
}
__device__ __forceinline__ float bflo(unsigned int u) { return __uint_as_float(u << 16); }
__device__ __forceinline__ float bfhi(unsigned int u) { return __uint_as_float(u & 0xffff0000u); }
__device__ __forceinline__ float softp(float a) {
  return (a > 15.f) ? a : __logf(1.f + __expf(a));
}

// ---------------- precompute, K-split partials ----------------
__global__ __launch_bounds__(256) void k_pre1(
    const float* __restrict__ W_in, const float* __restrict__ b_in,
    const float* __restrict__ W_inproj, const float* __restrict__ conv_w,
    const float* __restrict__ W_xproj, const float* __restrict__ W_dt,
    const float* __restrict__ A_log,
    const float* __restrict__ W_out, const float* __restrict__ W_fc,
    float* __restrict__ ws) {
  int bid = blockIdx.x, tid = threadIdx.x;
  if (bid < 768) {                       // Wf partials: 12x2048 out, K-split 8
    int ks = bid / 96;
    int out = (bid % 96) * 256 + tid;
    int r = out >> 11, c = out & 2047;
    int k0 = ks * 64;
    float acc = 0.f;
    for (int k = 0; k < 64; ++k) {
      float a = (r < NI) ? W_in[r * 512 + k0 + k] : b_in[k0 + k];
      acc = fmaf(a, W_inproj[(size_t)(k0 + k) * 2048 + c], acc);
    }
    ws[OFF_SA + (size_t)ks * 24576 + out] = acc;
  } else if (bid < 832) {                // A2
    int idx = (bid - 768) * 256 + tid;
    ws[OFF_A2 + idx] = -expf(A_log[idx]) * 1.4426950408889634f;
  } else if (bid < 1056) {               // Wof partials: 1024x7, K-split 8
    int lb = bid - 832;
    int ks = lb / 28;
    int out = (lb % 28) * 256 + tid;
    int d = out / NC, cc = out - d * NC;
    int k0 = ks * 64;
    float acc = 0.f;
    for (int k = 0; k < 64; ++k)
      acc = fmaf(W_out[d * 512 + k0 + k], W_fc[(k0 + k) * NC + cc], acc);
    ws[OFF_SC + (size_t)ks * 7168 + out] = acc;
  } else if (bid < 1072) {               // conv_w^T
    int idx = (bid - 1056) * 256 + tid;
    int k = idx >> 10, dd = idx & 1023;
    ws[OFF_CWT + idx] = conv_w[dd * 4 + k];
  } else if (bid < 1328) {               // W_xproj^T -> bf16 [64][1024]
    int idx = (bid - 1072) * 256 + tid;  // 65536
    int c = idx >> 10, k = idx & 1023;
    unsigned short* wxh = (unsigned short*)(ws + OFF_WXH);
    wxh[idx] = f2bf(W_xproj[(size_t)k * 64 + c]);
  } else {                               // W_dt^T -> f16 [1024 d][32 k]
    int idx = (bid - 1328) * 256 + tid;  // 32768
    int dd = idx >> 5, k = idx & 31;
    unsigned short* wdh = (unsigned short*)(ws + OFF_WDTH);
    wdh[idx] = f2h_u(W_dt[(size_t)k * DI + dd]);
  }
}

__global__ __launch_bounds__(256) void k_pre2(float* __restrict__ ws) {
  int idx = blockIdx.x * 256 + threadIdx.x;  // 31744 total
  if (idx < 24576) {
    float acc = 0.f;
    for (int ks = 0; ks < 8; ++ks) acc += ws[OFF_SA + (size_t)ks * 24576 + idx];
    int r = idx >> 11, c = idx & 2047;
    if (r < NI) ws[OFF_WF + (size_t)r * 2048 + c] = acc;
    else ws[OFF_BF + c] = acc;
  } else {
    int i2 = idx - 24576;
    float acc = 0.f;
    for (int ks = 0; ks < 8; ++ks) acc += ws[OFF_SC + (size_t)ks * 7168 + i2];
    ws[OFF_WOF + i2] = acc;
  }
}

// ---------------- u = silu(conv(in_proj_u)) -> bf16; 8 t per block ----------------
__global__ __launch_bounds__(256) void k_u(
    const float* __restrict__ xe, const float* __restrict__ xm,
    const float* __restrict__ conv_b, float* __restrict__ ws) {
  __shared__ float scat[11][11];
  int bid = blockIdx.x, tid = threadIdx.x;
  int tg = bid >> 2, dq = bid & 3;
  int d = dq * 256 + tid;
  int b = tg >> 8;
  int t0 = (tg & 255) * 8;
  if (tid < 121) {
    int k = tid / 11, i = tid - k * 11;
    int tp = t0 - 3 + k;
    float v = 0.f;
    if (tp >= 0) v = (i < 7) ? xe[(size_t)(b * LL + tp) * 7 + i]
                             : xm[(size_t)(b * LL + tp) * 4 + (i - 7)];
    scat[k][i] = v;
  }
  __syncthreads();
  float wfv[NI];
#pragma unroll
  for (int i = 0; i < NI; ++i) wfv[i] = ws[OFF_WF + (size_t)i * 2048 + d];
  float bfu = ws[OFF_BF + d];
  float cwv[4];
#pragma unroll
  for (int k = 0; k < 4; ++k) cwv[k] = ws[OFF_CWT + k * 1024 + d];
  float cbv = conv_b[d];
  float xzv[11];
#pragma unroll
  for (int w2 = 0; w2 < 11; ++w2) {
    int tp = t0 - 3 + w2;
    float xz = bfu;
#pragma unroll
    for (int i = 0; i < NI; ++i) xz = fmaf(scat[w2][i], wfv[i], xz);
    xzv[w2] = (tp >= 0) ? xz : 0.f;
  }
  unsigned short* uhp = (unsigned short*)(ws + OFF_UH);
#pragma unroll
  for (int tt = 0; tt < 8; ++tt) {
    float acc = cbv;
#pragma unroll
    for (int k = 0; k < 4; ++k) acc = fmaf(cwv[k], xzv[tt + k], acc);
    float uval = acc / (1.f + __expf(-acc));
    uhp[(size_t)(b * LL + t0 + tt) * DI + d] = f2bf(uval);
  }
}

// ---------------- x_proj GEMM via bf16 MFMA: 16384x64x1024 ----------------
__global__ __launch_bounds__(256) void k_proj(float* __restrict__ ws) {
  __shared__ unsigned short su[64][72];   // u tile   [row][k]
  __shared__ unsigned short sw[64][72];   // WxT tile [col][k]
  const unsigned short* uh  = (const unsigned short*)(ws + OFF_UH);
  const unsigned short* wxh = (const unsigned short*)(ws + OFF_WXH);
  int bid = blockIdx.x, tid = threadIdx.x;
  int r0 = bid * 64;
  int lane = tid & 63, w = tid >> 6;
  int srow = tid >> 3, skg = tid & 7;     // staging: 32 rows x 8 kgroups
  uint4 ru[2][2], rw[2][2];
  const ushort* ub0 = uh + (size_t)(r0 + srow) * DI + skg * 8;
  const ushort* wb0 = wxh + (size_t)srow * DI + skg * 8;
  ru[0][0] = *(const uint4*)(ub0);
  ru[0][1] = *(const uint4*)(ub0 + (size_t)32 * DI);
  rw[0][0] = *(const uint4*)(wb0);
  rw[0][1] = *(const uint4*)(wb0 + (size_t)32 * DI);
  ru[1][0] = *(const uint4*)(ub0 + 64);
  ru[1][1] = *(const uint4*)(ub0 + (size_t)32 * DI + 64);
  rw[1][0] = *(const uint4*)(wb0 + 64);
  rw[1][1] = *(const uint4*)(wb0 + (size_t)32 * DI + 64);
  f32x4 acc[4];
#pragma unroll
  for (int i = 0; i < 4; ++i) acc[i] = (f32x4){0.f, 0.f, 0.f, 0.f};
  int arow = w * 16 + (lane & 15);
  for (int kt = 0; kt < 16; ++kt) {
    int set = kt & 1;
    __syncthreads();
    *(uint4*)&su[srow][skg * 8]      = ru[set][0];
    *(uint4*)&su[srow + 32][skg * 8] = ru[set][1];
    *(uint4*)&sw[srow][skg * 8]      = rw[set][0];
    *(uint4*)&sw[srow + 32][skg * 8] = rw[set][1];
    __syncthreads();
    if (kt + 2 < 16) {
      int ko = (kt + 2) * 64;
      ru[set][0] = *(const uint4*)(ub0 + ko);
      ru[set][1] = *(const uint4*)(ub0 + (size_t)32 * DI + ko);
      rw[set][0] = *(const uint4*)(wb0 + ko);
      rw[set][1] = *(const uint4*)(wb0 + (size_t)32 * DI + ko);
    }
#pragma unroll
    for (int ks = 0; ks < 2; ++ks) {
      int koff = ks * 32 + (lane >> 4) * 8;
      bf16x8 av = *(const bf16x8*)&su[arow][koff];
#pragma unroll
      for (int nt = 0; nt < 4; ++nt) {
        bf16x8 bv = *(const bf16x8*)&sw[nt * 16 + (lane & 15)][koff];
        acc[nt] = __builtin_amdgcn_mfma_f32_16x16x32_bf16(av, bv, acc[nt], 0, 0, 0);
      }
    }
  }
  int orow = r0 + w * 16 + ((lane >> 4) << 2);
  int ocol = lane & 15;
  unsigned short* dlh = (unsigned short*)(ws + OFF_DLH);
#pragma unroll
  for (int reg = 0; reg < 4; ++reg) {
    size_t rr = orow + reg;
    dlh[rr * 32 + ocol]      = f2h_u(acc[0][reg]);
    dlh[rr * 32 + 16 + ocol] = f2h_u(acc[1][reg]);
    ws[OFF_BC + rr * NS + ocol] = acc[2][reg];
    ws[OFF_CC + rr * NS + ocol] = acc[3][reg];
  }
}

// ---------------- dt = softplus(dt_lo @ W_dt + b_dt) via f16 MFMA ----------------
__global__ __launch_bounds__(256) void k_dt(
    const float* __restrict__ b_dt, float* __restrict__ ws) {
  __shared__ _Float16 sdl[64][32];
  const unsigned short* dlh = (const unsigned short*)(ws + OFF_DLH);
  const unsigned short* wdh = (const unsigned short*)(ws + OFF_WDTH);
  unsigned short* dth = (unsigned short*)(ws + OFF_DTH);
  int bid = blockIdx.x, tid = threadIdx.x;
  size_t r0 = (size_t)bid * 64;
  {
    int row = tid >> 2, q = tid & 3;
    *(uint4*)&sdl[row][q * 8] = *(const uint4*)&dlh[(r0 + row) * 32 + q * 8];
  }
  __syncthreads();
  int lane = tid & 63, w = tid >> 6;
  int col = lane & 15, kg = lane >> 4;
  f16x8 af = *(const f16x8*)&sdl[w * 16 + col][kg * 8];
  for (int dt4 = 0; dt4 < 64; ++dt4) {
    f16x8 bf8 = *(const f16x8*)&wdh[(size_t)(dt4 * 16 + col) * 32 + kg * 8];
    f32x4 acc = (f32x4){0.f, 0.f, 0.f, 0.f};
    acc = __builtin_amdgcn_mfma_f32_16x16x32_f16(af, bf8, acc, 0, 0, 0);
    float bdt = b_dt[dt4 * 16 + col];
    size_t orow = r0 + (size_t)w * 16 + (size_t)kg * 4;   // FIX: wave tile base w*16
#pragma unroll
    for (int r = 0; r < 4; ++r) {
      float v = acc[r] + bdt;
      dth[(orow + r) * DI + dt4 * 16 + col] = f2h_u(softp(v));
    }
  }
}

// ---------------- scan pass 1: per-chunk local scan + decay product ----------------
#define SC_LC 64
__global__ __launch_bounds__(256) void k_scan1(float* __restrict__ ws) {
  __shared__ float sdt[SC_LC][64];
  __shared__ float suu[SC_LC][64];
  __shared__ float sBB[SC_LC][16];
  int bid = blockIdx.x, tid = threadIdx.x;   // 4096 blocks
  int b = bid >> 9, dblk = (bid >> 5) & 15, ch = bid & 31;
  int d0 = dblk * 64, t0 = ch * 64;
  const unsigned short* dth = (const unsigned short*)(ws + OFF_DTH) +
                              ((size_t)(b * LL + t0)) * DI + d0;
  const unsigned short* uh = (const unsigned short*)(ws + OFF_UH) +
                             ((size_t)(b * LL + t0)) * DI + d0;
  const float* Bp = ws + OFF_BC + ((size_t)(b * LL + t0)) * NS;
#pragma unroll
  for (int i = 0; i < 2; ++i) {
    int idx = tid + i * 256;
    int row = idx >> 3, q = idx & 7;
    uint4 v = *(const uint4*)&dth[(size_t)row * DI + q * 8];
    f16x8 hv = *(f16x8*)&v;
    float4 f0 = {(float)hv[0], (float)hv[1], (float)hv[2], (float)hv[3]};
    float4 f1 = {(float)hv[4], (float)hv[5], (float)hv[6], (float)hv[7]};
    *(float4*)&sdt[row][q * 8]     = f0;
    *(float4*)&sdt[row][q * 8 + 4] = f1;
    uint4 vu = *(const uint4*)&uh[(size_t)row * DI + q * 8];
    float4 g0 = {bflo(vu.x), bfhi(vu.x), bflo(vu.y), bfhi(vu.y)};
    float4 g1 = {bflo(vu.z), bfhi(vu.z), bflo(vu.w), bfhi(vu.w)};
    *(float4*)&suu[row][q * 8]     = g0;
    *(float4*)&suu[row][q * 8 + 4] = g1;
  }
  {
    int row = tid >> 2, q = tid & 3;
    *(float4*)&sBB[row][q * 4] = *(const float4*)&Bp[(size_t)row * NS + q * 4];
  }
  __syncthreads();
  int dl = tid & 63, sq = tid >> 6, s0 = sq * 4;
  int d = d0 + dl;
  float A2v[4];
#pragma unroll
  for (int j = 0; j < 4; ++j) A2v[j] = ws[OFF_A2 + (size_t)d * NS + s0 + j];
  float h0 = 0.f, h1 = 0.f, h2 = 0.f, h3 = 0.f, S = 0.f;
#pragma unroll 4
  for (int t = 0; t < SC_LC; ++t) {
    float dtv = sdt[t][dl];
    float uv  = suu[t][dl];
    f32x4 bv = *(const f32x4*)&sBB[t][s0];
    S += dtv;
    float dtu = dtv * uv;
    h0 = fmaf(fexp2(dtv * A2v[0]), h0, bv[0] * dtu);
    h1 = fmaf(fexp2(dtv * A2v[1]), h1, bv[1] * dtu);
    h2 = fmaf(fexp2(dtv * A2v[2]), h2, bv[2] * dtu);
    h3 = fmaf(fexp2(dtv * A2v[3]), h3, bv[3] * dtu);
  }
  size_t base = (((size_t)b * 32 + ch) * 1024 + d) * 16 + s0;
  float4 P = {fexp2(A2v[0] * S), fexp2(A2v[1] * S), fexp2(A2v[2] * S), fexp2(A2v[3] * S)};
  float4 H = {h0, h1, h2, h3};
  *(float4*)&ws[OFF_PB + base] = P;
  *(float4*)&ws[OFF_HB + base] = H;
}

// ---------------- scan pass 2: combine chunk states ----------------
__global__ __launch_bounds__(256) void k_comb(float* __restrict__ ws) {
  int gid = blockIdx.x * 256 + threadIdx.x;  // 131072 = [b][d][s]
  int s = gid & 15, d = (gid >> 4) & 1023, b = gid >> 14;
  const float* Pb = ws + OFF_PB;
  const float* Hb = ws + OFF_HB;
  size_t stride = (size_t)1024 * 16;
  size_t base = ((size_t)b * 32) * stride + (size_t)d * 16 + s;
  float h = 0.f;
#pragma unroll 6
  for (int c = 0; c < 30; ++c)
    h = fmaf(Pb[base + c * stride], h, Hb[base + c * stride]);
  ws[OFF_H30 + gid] = h;
  ws[OFF_H31 + gid] = fmaf(Pb[base + 30 * stride], h, Hb[base + 30 * stride]);
}

// ---------------- scan pass 3: tail chunks 30/31 with y output ----------------
__global__ __launch_bounds__(256) void k_tail(
    const float* __restrict__ Dvec, float* __restrict__ ws) {
  __shared__ float sdt[SC_LC][64];
  __shared__ float suu[SC_LC][64];
  __shared__ float sBB[SC_LC][16];
  __shared__ float sCC[SC_LC][16];
  int bid = blockIdx.x, tid = threadIdx.x;   // 256 blocks
  int b = bid >> 5, dblk = (bid >> 1) & 15, half = bid & 1;
  int d0 = dblk * 64, t0 = (30 + half) * 64;
  const unsigned short* dth = (const unsigned short*)(ws + OFF_DTH) +
                              ((size_t)(b * LL + t0)) * DI + d0;
  const unsigned short* uh = (const unsigned short*)(ws + OFF_UH) +
                             ((size_t)(b * LL + t0)) * DI + d0;
  const float* Bp = ws + OFF_BC + ((size_t)(b * LL + t0)) * NS;
  const float* Cp = ws + OFF_CC + ((size_t)(b * LL + t0)) * NS;
#pragma unroll
  for (int i = 0; i < 2; ++i) {
    int idx = tid + i * 256;
    int row = idx >> 3, q = idx & 7;
    uint4 v = *(const uint4*)&dth[(size_t)row * DI + q * 8];
    f16x8 hv = *(f16x8*)&v;
    float4 f0 = {(float)hv[0], (float)hv[1], (float)hv[2], (float)hv[3]};
    float4 f1 = {(float)hv[4], (float)hv[5], (float)hv[6], (float)hv[7]};
    *(float4*)&sdt[row][q * 8]     = f0;
    *(float4*)&sdt[row][q * 8 + 4] = f1;
    uint4 vu = *(const uint4*)&uh[(size_t)row * DI + q * 8];
    float4 g0 = {bflo(vu.x), bfhi(vu.x), bflo(vu.y), bfhi(vu.y)};
    float4 g1 = {bflo(vu.z), bfhi(vu.z), bflo(vu.w), bfhi(vu.w)};
    *(float4*)&suu[row][q * 8]     = g0;
    *(float4*)&suu[row][q * 8 + 4] = g1;
  }
  {
    int row = tid >> 2, q = tid & 3;
    *(float4*)&sBB[row][q * 4] = *(const float4*)&Bp[(size_t)row * NS + q * 4];
    *(float4*)&sCC[row][q * 4] = *(const float4*)&Cp[(size_t)row * NS + q * 4];
  }
  __syncthreads();
  // thread remap: dl = tid>>2 (within-wave groups of 4), sq = tid&3
  int dl = tid >> 2, sq = tid & 3, s0 = sq * 4;
  int d = d0 + dl;
  float A2v[4];
#pragma unroll
  for (int j = 0; j < 4; ++j) A2v[j] = ws[OFF_A2 + (size_t)d * NS + s0 + j];
  float Dv = Dvec[d];
  float4 hv = *(const float4*)&ws[(half ? OFF_H31 : OFF_H30) +
                                  ((size_t)b << 14) + ((size_t)d << 4) + s0];
  float h0 = hv.x, h1 = hv.y, h2 = hv.z, h3 = hv.w;
  float* ysp = ws + OFF_YS;
  int tstart = half ? 0 : 32;
  for (int t = 0; t < SC_LC; ++t) {
    float dtv = sdt[t][dl];
    float uv  = suu[t][dl];
    f32x4 bv = *(const f32x4*)&sBB[t][s0];
    float dtu = dtv * uv;
    h0 = fmaf(fexp2(dtv * A2v[0]), h0, bv[0] * dtu);
    h1 = fmaf(fexp2(dtv * A2v[1]), h1, bv[1] * dtu);
    h2 = fmaf(fexp2(dtv * A2v[2]), h2, bv[2] * dtu);
    h3 = fmaf(fexp2(dtv * A2v[3]), h3, bv[3] * dtu);
    if (t >= tstart) {
      f32x4 cv = *(const f32x4*)&sCC[t][s0];
      float pv = h0 * cv[0] + h1 * cv[1] + h2 * cv[2] + h3 * cv[3];
      pv += __shfl_xor(pv, 1);
      pv += __shfl_xor(pv, 2);
      if (sq == 0)
        ysp[((size_t)(b * PRED + (t0 + t - (LL - PRED)))) * DI + d] = fmaf(Dv, uv, pv);
    }
  }
}

// ---------------- z-gate + fused out_proj@W_fc ----------------
__global__ __launch_bounds__(256) void k_out(
    const float* __restrict__ xe, const float* __restrict__ xm,
    const float* __restrict__ b_fc, const float* __restrict__ ws,
    float* __restrict__ out) {
  __shared__ float scat[NI];
  __shared__ float sacc[4][NC];
  int bid = blockIdx.x, tid = threadIdx.x;
  int b = bid / PRED, p = bid - b * PRED;
  int t = LL - PRED + p;
  if (tid < NI) scat[tid] = (tid < 7) ? xe[(size_t)(b * LL + t) * 7 + tid]
                                      : xm[(size_t)(b * LL + t) * 4 + (tid - 7)];
  __syncthreads();
  const float* Wf  = ws + OFF_WF;
  const float* bf  = ws + OFF_BF;
  const float* Wof = ws + OFF_WOF;
  const float* ysp = ws + OFF_YS + ((size_t)bid) * DI;
  float acc[NC];
#pragma unroll
  for (int cc = 0; cc < NC; ++cc) acc[cc] = 0.f;
#pragma unroll
  for (int j = 0; j < 4; ++j) {
    int dd = tid + j * 256;
    float zv = bf[DI + dd];
#pragma unroll
    for (int i = 0; i < NI; ++i) zv = fmaf(scat[i], Wf[(size_t)i * 2048 + DI + dd], zv);
    float g = ysp[dd] * (zv / (1.f + __expf(-zv)));
#pragma unroll
    for (int cc = 0; cc < NC; ++cc) acc[cc] = fmaf(g, Wof[dd * NC + cc], acc[cc]);
  }
#pragma unroll
  for (int cc = 0; cc < NC; ++cc) {
    float v = acc[cc];
    for (int off = 32; off > 0; off >>= 1) v += __shfl_down(v, off);
    if ((tid & 63) == 0) sacc[tid >> 6][cc] = v;
  }
  __syncthreads();
  if (tid < NC)
    out[(size_t)bid * NC + tid] =
        sacc[0][tid] + sacc[1][tid] + sacc[2][tid] + sacc[3][tid] + b_fc[tid];
}

extern "C" void kernel_launch(void* const* d_in, const int* in_sizes, int n_in,
                              void* d_out, int out_size, void* d_ws, size_t ws_size,
                              hipStream_t stream) {
  const float* xe    = (const float*)d_in[0];
  const float* xm    = (const float*)d_in[1];
  const float* W_in  = (const float*)d_in[4];
  const float* b_in  = (const float*)d_in[5];
  const float* W_ip  = (const float*)d_in[6];
  const float* cw    = (const float*)d_in[7];
  const float* cb    = (const float*)d_in[8];
  const float* W_xp  = (const float*)d_in[9];
  const float* W_dt  = (const float*)d_in[10];
  const float* b_dt  = (const float*)d_in[11];
  const float* A_log = (const float*)d_in[12];
  const float* Dv    = (const float*)d_in[13];
  const float* W_out = (const float*)d_in[14];
  const float* W_fc  = (const float*)d_in[15];
  const float* b_fc  = (const float*)d_in[16];
  float* ws  = (float*)d_ws;
  float* out = (float*)d_out;

  k_pre1 <<<1456, 256, 0, stream>>>(W_in, b_in, W_ip, cw, W_xp, W_dt, A_log, W_out, W_fc, ws);
  k_pre2 <<<124, 256, 0, stream>>>(ws);
  k_u    <<<8192, 256, 0, stream>>>(xe, xm, cb, ws);
  k_proj <<<256, 256, 0, stream>>>(ws);
  k_dt   <<<256, 256, 0, stream>>>(b_dt, ws);
  k_scan1<<<4096, 256, 0, stream>>>(ws);
  k_comb <<<512, 256, 0, stream>>>(ws);
  k_tail <<<256, 256, 0, stream>>>(Dv, ws);
  k_out  <<<BB * PRED, 256, 0, stream>>>(xe, xm, b_fc, ws, out);
}